// Round 5
// baseline (256.479 us; speedup 1.0000x reference)
//
#include <hip/hip_runtime.h>

typedef __attribute__((ext_vector_type(8))) short short8;
typedef __attribute__((ext_vector_type(4))) short short4v;
typedef __attribute__((ext_vector_type(4))) float float4v;
typedef __attribute__((ext_vector_type(8))) __bf16 bf16x8;

// LDS layout (bytes):
//   region A  [0, 57344)        : XT bf16[49][512] (swizzled) during GEMMs; VT[8][64][56] after V
//   PQ        [57344, 107520)   : P_q bf16 flat s*128+dd*2 (swizzled)   (50176 B)
//   PK        [107520, 157696)  : P_k same
//   attn ovl  [57344, 122880)   : per-head attn bf16 [64][64] swizzled (overlays PQ/PK after QK^T)
//   BIAS      [157696, 163104)  : bias_table f32 [169][8]
#define LDS_PQ 57344
#define LDS_PK 107520
#define LDS_BIAS 157696
#define LDS_TOTAL 163104

__device__ __forceinline__ unsigned short f2bf(float f) {
  unsigned u = __float_as_uint(f);
  u += 0x7FFFu + ((u >> 16) & 1u);   // RNE
  return (unsigned short)(u >> 16);
}

// ---- kernel 1: convert q_w/k_w/v_w fp32 -> bf16 into workspace ----
__global__ void wconv_kernel(const float* __restrict__ qw, const float* __restrict__ kw,
                             const float* __restrict__ vw, short* __restrict__ out) {
  int g = blockIdx.x >> 8;  // 0:q 1:k 2:v
  const float* src = (g == 0) ? qw : (g == 1) ? kw : vw;
  int off = ((blockIdx.x & 255) * 256 + threadIdx.x) * 4;
  float4v v = *(const float4v*)(src + off);
  short4v o;
  o.x = (short)f2bf(v.x); o.y = (short)f2bf(v.y);
  o.z = (short)f2bf(v.z); o.w = (short)f2bf(v.w);
  *(short4v*)(out + g * 262144 + off) = o;
}

// ---- kernel 2: fused windowed attention, one 1024-thread workgroup per (b, window) ----
// 16 waves, all co-resident (LDS caps at 1 block/CU) -> hard 128-reg/wave budget.
// Round-4 left the kernel latency-bound (Mfma 16%, VALU 22%, occ 46%): the kk
// loop exposed ~120cy LDS + ~200cy L2 latency each iteration. This round:
// 2x-unrolled ping-pong software pipeline, 1-deep prefetch of BOTH the LDS
// a-fragments and the global b-fragments. Wraparound prefetch keeps a(0)
// resident across the g loop (A identical for q/k/v). #pragma unroll 1 stays
// (round-3 lesson: compiler hoist -> 290 MB spill traffic at the 128-reg cap).
__global__ __launch_bounds__(1024, 4) void wattn_kernel(
    const float* __restrict__ x, const short* __restrict__ wcvt,
    const float* __restrict__ qb, const float* __restrict__ kb, const float* __restrict__ vb,
    const float* __restrict__ btab, float* __restrict__ out) {
  __shared__ __align__(16) char sm[LDS_TOTAL];
  const int tid  = threadIdx.x;
  const int lane = tid & 63;
  const int wave = tid >> 6;       // 0..15
  const int bwi  = blockIdx.x;     // b*64 + wi
  const int bb   = bwi >> 6, wi = bwi & 63;
  const int l15  = lane & 15;
  const int l4   = lane >> 4;
  const int ig   = l4 * 4;

  // stage bias table (f32, 169*8)
  for (int i = tid; i < 169 * 8; i += 1024)
    *(float*)(sm + LDS_BIAS + i * 4) = btab[i];

  // stage x tile -> XT bf16 [49][512], row-XOR swizzle
  {
    const float* xb = x + (size_t)bb * (3136 * 512);
    const int whi = (wi >> 3) * 7, wlo = (wi & 7) * 7;
    for (int idx = tid; idx < 49 * 128; idx += 1024) {
      int t = idx >> 7, c4 = idx & 127;
      int yt = (t * 37) >> 8, xt = t - yt * 7;
      int l = (whi + yt) * 56 + wlo + xt;
      float4v v = *(const float4v*)(xb + l * 512 + c4 * 4);
      short4v o;
      o.x = (short)f2bf(v.x); o.y = (short)f2bf(v.y);
      o.z = (short)f2bf(v.z); o.w = (short)f2bf(v.w);
      int byte = t * 1024 + c4 * 8;
      *(short4v*)(sm + (byte ^ ((t & 7) << 4))) = o;
    }
  }
  __syncthreads();

  const int wcol = wave * 32;
  const int c0   = l4 * 16;        // byte k-offset within XT row for this lane

  // per-m A-read address components (row >= 49 reads junk; discarded row-locally)
  int abase[4], asw[4];
#pragma unroll
  for (int m = 0; m < 4; ++m) {
    int row = m * 16 + l15;
    abase[m] = row * 1024;
    asw[m]   = (row & 7) << 4;
  }

  // pipeline registers (live across the g loop)
  bf16x8 aA[4], aB[4];
#pragma unroll
  for (int m = 0; m < 4; ++m)
    aA[m] = __builtin_bit_cast(bf16x8, *(const short8*)(sm + abase[m] + (c0 ^ asw[m])));  // a(kk=0)

  // ---- three projection GEMMs: P = XT @ W^T + b ----
  for (int g = 0; g < 3; ++g) {
    const short* wt = wcvt + g * 262144;
    const float* bias = (g == 0) ? qb : (g == 1) ? kb : vb;
    float4v acc[4][2];
#pragma unroll
    for (int m = 0; m < 4; ++m)
#pragma unroll
      for (int n = 0; n < 2; ++n) acc[m][n] = (float4v)0.f;

    const short* wp0 = wt + (wcol + l15) * 512 + l4 * 8;
    const short* wp1 = wp0 + 16 * 512;
    bf16x8 b0 = __builtin_bit_cast(bf16x8, *(const short8*)(wp0));
    bf16x8 b1 = __builtin_bit_cast(bf16x8, *(const short8*)(wp1));

#pragma unroll 1
    for (int kk = 0; kk < 16; kk += 2) {
      // phase A: prefetch a(kk+1)->aB, b(kk+1); MFMA on aA/b0/b1
      const int offB = ((kk + 1) * 64 + c0);
#pragma unroll
      for (int m = 0; m < 4; ++m)
        aB[m] = __builtin_bit_cast(bf16x8, *(const short8*)(sm + abase[m] + (offB ^ asw[m])));
      bf16x8 nb0 = __builtin_bit_cast(bf16x8, *(const short8*)(wp0 + (kk + 1) * 32));
      bf16x8 nb1 = __builtin_bit_cast(bf16x8, *(const short8*)(wp1 + (kk + 1) * 32));
#pragma unroll
      for (int m = 0; m < 4; ++m) {
        acc[m][0] = __builtin_amdgcn_mfma_f32_16x16x32_bf16(aA[m], b0, acc[m][0], 0, 0, 0);
        acc[m][1] = __builtin_amdgcn_mfma_f32_16x16x32_bf16(aA[m], b1, acc[m][1], 0, 0, 0);
      }
      // phase B: prefetch a((kk+2)&15)->aA, b((kk+2)&15); MFMA on aB/nb0/nb1
      // (wraparound: loop exits with aA = a(0), reused by the next g)
      const int k2 = (kk + 2) & 15;
      const int offA = (k2 * 64 + c0);
#pragma unroll
      for (int m = 0; m < 4; ++m)
        aA[m] = __builtin_bit_cast(bf16x8, *(const short8*)(sm + abase[m] + (offA ^ asw[m])));
      b0 = __builtin_bit_cast(bf16x8, *(const short8*)(wp0 + k2 * 32));
      b1 = __builtin_bit_cast(bf16x8, *(const short8*)(wp1 + k2 * 32));
#pragma unroll
      for (int m = 0; m < 4; ++m) {
        acc[m][0] = __builtin_amdgcn_mfma_f32_16x16x32_bf16(aB[m], nb0, acc[m][0], 0, 0, 0);
        acc[m][1] = __builtin_amdgcn_mfma_f32_16x16x32_bf16(aB[m], nb1, acc[m][1], 0, 0, 0);
      }
    }

    if (g < 2) {
      const int base = (g == 0) ? LDS_PQ : LDS_PK;
#pragma unroll
      for (int n = 0; n < 2; ++n) {
        int o = wcol + n * 16 + l15;
        float bv = bias[o];
#pragma unroll
        for (int m = 0; m < 4; ++m)
#pragma unroll
          for (int r = 0; r < 4; ++r) {
            int t = m * 16 + ig + r;
            if (t < 49) {
              int s = t * 8 + (o >> 6);
              int flat = s * 128 + (o & 63) * 2;
              *(unsigned short*)(sm + base + (flat ^ ((s & 7) << 4))) = f2bf(acc[m][n][r] + bv);
            }
          }
      }
    } else {
      __syncthreads();  // all waves done reading XT; region A becomes VT
#pragma unroll
      for (int n = 0; n < 2; ++n) {
        int o = wcol + n * 16 + l15;
        float bv = bias[o];
        int dd = o & 63;
#pragma unroll
        for (int m = 0; m < 4; ++m)
#pragma unroll
          for (int r = 0; r < 4; ++r) {
            int t = m * 16 + ig + r;
            if (t < 49) {
              int s = t * 8 + (o >> 6);
              int h2 = (s * 1339) >> 16;       // s / 49
              int tp = s - h2 * 49;
              *(unsigned short*)(sm + h2 * 7168 + dd * 112 + tp * 2) = f2bf(acc[m][n][r] + bv);
            }
          }
      }
      // zero VT pads t' = 49..55 (0*NaN=NaN inside MFMA -> pads must be real zeros)
      if (tid < 512) {
        int h2 = tid >> 6, dd = tid & 63;
        char* p = sm + h2 * 7168 + dd * 112;
#pragma unroll
        for (int q = 49; q < 56; ++q) *(unsigned short*)(p + q * 2) = 0;
      }
      __syncthreads();
    }
  }

  // ---- attention: wave pair (h, h+8) -> head h; 'half' owns row m-tiles {half*2, half*2+1} ----
  const int h    = wave & 7;
  const int half = wave >> 3;
  const float* bias_f = (const float*)(sm + LDS_BIAS);

  float4v sc[2][4];
#pragma unroll
  for (int mm = 0; mm < 2; ++mm)
#pragma unroll
    for (int n = 0; n < 4; ++n) sc[mm][n] = (float4v)0.f;

#pragma unroll
  for (int ks = 0; ks < 2; ++ks) {
    const int dd = ks * 32 + l4 * 8;
    bf16x8 a[2], b[4];
#pragma unroll
    for (int mm = 0; mm < 2; ++mm) {
      int s = h * 49 + (half * 2 + mm) * 16 + l15;   // rows >=49: junk, discarded
      int flat = s * 128 + dd * 2;
      a[mm] = __builtin_bit_cast(bf16x8, *(const short8*)(sm + LDS_PQ + (flat ^ ((s & 7) << 4))));
    }
#pragma unroll
    for (int n = 0; n < 4; ++n) {
      int s = h * 49 + n * 16 + l15;                 // cols >=49: junk, masked by index below
      int flat = s * 128 + dd * 2;
      b[n] = __builtin_bit_cast(bf16x8, *(const short8*)(sm + LDS_PK + (flat ^ ((s & 7) << 4))));
    }
#pragma unroll
    for (int mm = 0; mm < 2; ++mm)
#pragma unroll
      for (int n = 0; n < 4; ++n)
        sc[mm][n] = __builtin_amdgcn_mfma_f32_16x16x32_bf16(a[mm], b[n], sc[mm][n], 0, 0, 0);
  }

  // softmax on this wave's rows, in place (row i spread over 16 lanes x 4 n-tiles)
  // invalid (i,j) slots carry -1e30; exp underflows them to exact 0 (no compare needed)
#pragma unroll
  for (int mm = 0; mm < 2; ++mm)
#pragma unroll
    for (int r = 0; r < 4; ++r) {
      int i = (half * 2 + mm) * 16 + ig + r;
      int yi = (i * 37) >> 8, xi = i - yi * 7;
      float mx = -1e30f;
#pragma unroll
      for (int n = 0; n < 4; ++n) {
        int j = n * 16 + l15;
        float v = -1e30f;
        if (i < 49 && j < 49) {
          int yj = (j * 37) >> 8, xj = j - yj * 7;
          int idx = (yi - yj + 6) * 13 + (xi - xj + 6);
          v = sc[mm][n][r] * 0.125f + bias_f[idx * 8 + h];
        }
        sc[mm][n][r] = v;
        mx = fmaxf(mx, v);
      }
      mx = fmaxf(mx, __shfl_xor(mx, 1));
      mx = fmaxf(mx, __shfl_xor(mx, 2));
      mx = fmaxf(mx, __shfl_xor(mx, 4));
      mx = fmaxf(mx, __shfl_xor(mx, 8));
      float ssum = 0.f;
#pragma unroll
      for (int n = 0; n < 4; ++n) {
        float e = __expf(sc[mm][n][r] - mx);   // -1e30 slots underflow to 0
        sc[mm][n][r] = e;
        ssum += e;
      }
      ssum += __shfl_xor(ssum, 1);
      ssum += __shfl_xor(ssum, 2);
      ssum += __shfl_xor(ssum, 4);
      ssum += __shfl_xor(ssum, 8);
      float inv = 1.f / ssum;
#pragma unroll
      for (int n = 0; n < 4; ++n) sc[mm][n][r] *= inv;
    }

  __syncthreads();  // Pq/Pk dead for ALL waves -> overlay attn (per head, [64][64] bf16 swizzled)
  const int ovb = LDS_PQ + h * 8192;
#pragma unroll
  for (int mm = 0; mm < 2; ++mm)
#pragma unroll
    for (int r = 0; r < 4; ++r) {
      int i = (half * 2 + mm) * 16 + ig + r;
      if (i < 49) {
        int rowbase = i * 128;
        int swz = (i & 7) << 4;
#pragma unroll
        for (int n = 0; n < 4; ++n) {
          int j = n * 16 + l15;
          *(unsigned short*)(sm + ovb + ((rowbase + j * 2) ^ swz)) = f2bf(sc[mm][n][r]);
        }
      }
    }
  __syncthreads();

  // PV: out = attn @ V  (A rows = this wave's half; B from VT[h][dd][t'], full 64 cols)
  float4v oacc[2][4];
#pragma unroll
  for (int mm = 0; mm < 2; ++mm)
#pragma unroll
    for (int n = 0; n < 4; ++n) oacc[mm][n] = (float4v)0.f;

#pragma unroll
  for (int ks = 0; ks < 2; ++ks) {
    const int tp0 = ks * 32 + l4 * 8;
    bf16x8 a[2], b[4];
#pragma unroll
    for (int mm = 0; mm < 2; ++mm) {
      int i = (half * 2 + mm) * 16 + l15;            // rows >=49: junk, discarded
      int flat = i * 128 + tp0 * 2;
      a[mm] = __builtin_bit_cast(bf16x8, *(const short8*)(sm + ovb + (flat ^ ((i & 7) << 4))));
    }
    const int tt = (tp0 >= 56) ? 0 : tp0;  // clamp: attn cols >=49 are exact zeros
#pragma unroll
    for (int n = 0; n < 4; ++n) {
      int dd = n * 16 + l15;
      b[n] = __builtin_bit_cast(bf16x8, *(const short8*)(sm + h * 7168 + dd * 112 + tt * 2));
    }
#pragma unroll
    for (int mm = 0; mm < 2; ++mm)
#pragma unroll
      for (int n = 0; n < 4; ++n)
        oacc[mm][n] = __builtin_amdgcn_mfma_f32_16x16x32_bf16(a[mm], b[n], oacc[mm][n], 0, 0, 0);
  }

  // output: flat [b][wi][h][t'][dd]; full 256-B rows per wave
  float* op = out + (size_t)bwi * 25088 + h * 3136;
#pragma unroll
  for (int mm = 0; mm < 2; ++mm)
#pragma unroll
    for (int r = 0; r < 4; ++r) {
      int tp = (half * 2 + mm) * 16 + ig + r;
      if (tp < 49) {
#pragma unroll
        for (int n = 0; n < 4; ++n)
          op[tp * 64 + n * 16 + l15] = oacc[mm][n][r];
      }
    }
}

extern "C" void kernel_launch(void* const* d_in, const int* in_sizes, int n_in,
                              void* d_out, int out_size, void* d_ws, size_t ws_size,
                              hipStream_t stream) {
  const float* x    = (const float*)d_in[0];
  const float* q_w  = (const float*)d_in[1];
  const float* q_b  = (const float*)d_in[2];
  const float* k_w  = (const float*)d_in[3];
  const float* k_b  = (const float*)d_in[4];
  const float* v_w  = (const float*)d_in[5];
  const float* v_b  = (const float*)d_in[6];
  const float* btab = (const float*)d_in[7];
  short* wcvt = (short*)d_ws;  // 3 * 512 * 512 bf16 = 1.5 MB

  hipLaunchKernelGGL(wconv_kernel, dim3(768), dim3(256), 0, stream, q_w, k_w, v_w, wcvt);
  hipLaunchKernelGGL(wattn_kernel, dim3(1024), dim3(1024), 0, stream,
                     x, wcvt, q_b, k_b, v_b, btab, (float*)d_out);
}

// Round 6
// 253.697 us; speedup vs baseline: 1.0110x; 1.0110x over previous
//
#include <hip/hip_runtime.h>

typedef __attribute__((ext_vector_type(8))) short short8;
typedef __attribute__((ext_vector_type(4))) short short4v;
typedef __attribute__((ext_vector_type(4))) float float4v;
typedef __attribute__((ext_vector_type(8))) __bf16 bf16x8;

// LDS layout (bytes):
//   region A  [0, 57344)        : XT bf16[49][512] (swizzled) during GEMMs; VT[8][64][56] after V
//   PQ        [57344, 107520)   : P_q bf16 flat s*128+dd*2 (swizzled)   (50176 B)
//   PK        [107520, 157696)  : P_k same
//   attn ovl  [57344, 122880)   : per-head attn bf16 [64][64] swizzled (overlays PQ/PK after QK^T)
//   BIAS      [157696, 163104)  : bias_table f32 [169][8]
#define LDS_PQ 57344
#define LDS_PK 107520
#define LDS_BIAS 157696
#define LDS_TOTAL 163104

__device__ __forceinline__ unsigned short f2bf(float f) {
  unsigned u = __float_as_uint(f);
  u += 0x7FFFu + ((u >> 16) & 1u);   // RNE
  return (unsigned short)(u >> 16);
}

// ---- kernel 1: convert q_w/k_w/v_w fp32 -> bf16 into workspace ----
__global__ void wconv_kernel(const float* __restrict__ qw, const float* __restrict__ kw,
                             const float* __restrict__ vw, short* __restrict__ out) {
  int g = blockIdx.x >> 8;  // 0:q 1:k 2:v
  const float* src = (g == 0) ? qw : (g == 1) ? kw : vw;
  int off = ((blockIdx.x & 255) * 256 + threadIdx.x) * 4;
  float4v v = *(const float4v*)(src + off);
  short4v o;
  o.x = (short)f2bf(v.x); o.y = (short)f2bf(v.y);
  o.z = (short)f2bf(v.z); o.w = (short)f2bf(v.w);
  *(short4v*)(out + g * 262144 + off) = o;
}

// ---- kernel 2: fused windowed attention, one 1024-thread workgroup per (b, window) ----
// 16 waves, 1 block/CU (LDS-capped) -> hard 128-reg/wave budget; round-3/5
// lesson: any register growth spills (#pragma unroll 1 + shallow prefetch only).
// Round-6 change: OPERAND-SWAPPED MFMAs everywhere. Swapping A<->B transposes
// the C fragment so reg index r runs along the other output dim; with the same
// loads (roles swapped, byte-identical addresses) every epilogue becomes wide:
//   proj:  mfma(W, X)  -> r = 4 consecutive cols -> PQ/PK stored via ds_write_b64
//   QK^T:  mfma(K, Q)  -> lane holds 16 j of one i -> softmax = in-reg + 2 shfl;
//                         attn stored row-major via ds_write_b64
//   PV:    mfma(VT, A) -> D = out^T per-lane -> global_store_dwordx4 output
__global__ __launch_bounds__(1024, 4) void wattn_kernel(
    const float* __restrict__ x, const short* __restrict__ wcvt,
    const float* __restrict__ qb, const float* __restrict__ kb, const float* __restrict__ vb,
    const float* __restrict__ btab, float* __restrict__ out) {
  __shared__ __align__(16) char sm[LDS_TOTAL];
  const int tid  = threadIdx.x;
  const int lane = tid & 63;
  const int wave = tid >> 6;       // 0..15
  const int bwi  = blockIdx.x;     // b*64 + wi
  const int bb   = bwi >> 6, wi = bwi & 63;
  const int l15  = lane & 15;
  const int l4   = lane >> 4;
  const int ig   = l4 * 4;

  // stage bias table (f32, 169*8)
  for (int i = tid; i < 169 * 8; i += 1024)
    *(float*)(sm + LDS_BIAS + i * 4) = btab[i];

  // stage x tile -> XT bf16 [49][512], row-XOR swizzle
  {
    const float* xb = x + (size_t)bb * (3136 * 512);
    const int whi = (wi >> 3) * 7, wlo = (wi & 7) * 7;
    for (int idx = tid; idx < 49 * 128; idx += 1024) {
      int t = idx >> 7, c4 = idx & 127;
      int yt = (t * 37) >> 8, xt = t - yt * 7;
      int l = (whi + yt) * 56 + wlo + xt;
      float4v v = *(const float4v*)(xb + l * 512 + c4 * 4);
      short4v o;
      o.x = (short)f2bf(v.x); o.y = (short)f2bf(v.y);
      o.z = (short)f2bf(v.z); o.w = (short)f2bf(v.w);
      int byte = t * 1024 + c4 * 8;
      *(short4v*)(sm + (byte ^ ((t & 7) << 4))) = o;
    }
  }
  __syncthreads();

  const int wcol = wave * 32;

  // XT (B-operand) fragment address components; rows >=49 read junk, discarded
  int xbase[4], xsw[4];
#pragma unroll
  for (int mt = 0; mt < 4; ++mt) {
    int row = mt * 16 + l15;
    xbase[mt] = row * 1024;
    xsw[mt]   = (row & 7) << 4;
  }

  // ---- three projection GEMMs: P = XT @ W^T + b  (W as A-operand) ----
  for (int g = 0; g < 3; ++g) {
    const short* wt = wcvt + g * 262144;
    const float* bias = (g == 0) ? qb : (g == 1) ? kb : vb;
    float4v acc[2][4];   // [nt = o-tile][mt = t-tile]; D[row=o][col=t]
#pragma unroll
    for (int nt = 0; nt < 2; ++nt)
#pragma unroll
      for (int mt = 0; mt < 4; ++mt) acc[nt][mt] = (float4v)0.f;

    const short* wp0 = wt + (wcol + l15) * 512 + l4 * 8;
    const short* wp1 = wp0 + 16 * 512;
    bf16x8 w0 = __builtin_bit_cast(bf16x8, *(const short8*)(wp0));
    bf16x8 w1 = __builtin_bit_cast(bf16x8, *(const short8*)(wp1));

#pragma unroll 1
    for (int kk = 0; kk < 16; ++kk) {
      const int nko = ((kk + 1) & 15) * 32;      // wraps; extra loads discarded
      bf16x8 nw0 = __builtin_bit_cast(bf16x8, *(const short8*)(wp0 + nko));
      bf16x8 nw1 = __builtin_bit_cast(bf16x8, *(const short8*)(wp1 + nko));
      const int c = kk * 64 + l4 * 16;
      bf16x8 xf[4];
#pragma unroll
      for (int mt = 0; mt < 4; ++mt)
        xf[mt] = __builtin_bit_cast(bf16x8, *(const short8*)(sm + xbase[mt] + (c ^ xsw[mt])));
#pragma unroll
      for (int mt = 0; mt < 4; ++mt) {
        acc[0][mt] = __builtin_amdgcn_mfma_f32_16x16x32_bf16(w0, xf[mt], acc[0][mt], 0, 0, 0);
        acc[1][mt] = __builtin_amdgcn_mfma_f32_16x16x32_bf16(w1, xf[mt], acc[1][mt], 0, 0, 0);
      }
      w0 = nw0;
      w1 = nw1;
    }

    if (g < 2) {
      const int base = (g == 0) ? LDS_PQ : LDS_PK;
#pragma unroll
      for (int nt = 0; nt < 2; ++nt) {
        int o0 = wcol + nt * 16 + ig;            // o = o0 + r, r=0..3 (same head)
        float4v bv = *(const float4v*)(bias + o0);
        int dd0 = o0 & 63, sg = o0 >> 6;
#pragma unroll
        for (int mt = 0; mt < 4; ++mt) {
          int t = mt * 16 + l15;
          if (t < 49) {
            int s = t * 8 + sg;
            short4v pk;
#pragma unroll
            for (int r = 0; r < 4; ++r) pk[r] = (short)f2bf(acc[nt][mt][r] + bv[r]);
            *(short4v*)(sm + base + ((s * 128 + dd0 * 2) ^ ((s & 7) << 4))) = pk;
          }
        }
      }
    } else {
      __syncthreads();  // all waves done reading XT; region A becomes VT
#pragma unroll
      for (int nt = 0; nt < 2; ++nt) {
        int o0 = wcol + nt * 16 + ig;
        float4v bv = *(const float4v*)(bias + o0);
        int dd0 = o0 & 63, sg = o0 >> 6;
#pragma unroll
        for (int mt = 0; mt < 4; ++mt) {
          int t = mt * 16 + l15;
          if (t < 49) {
            int s = t * 8 + sg;
            int h2 = (s * 1339) >> 16;       // s / 49
            int tp = s - h2 * 49;
            char* p = sm + h2 * 7168 + tp * 2;
#pragma unroll
            for (int r = 0; r < 4; ++r)
              *(unsigned short*)(p + (dd0 + r) * 112) = f2bf(acc[nt][mt][r] + bv[r]);
          }
        }
      }
      // zero VT pads t' = 49..55 (0*NaN=NaN inside MFMA -> pads must be real zeros)
      if (tid < 512) {
        int h2 = tid >> 6, dd = tid & 63;
        char* p = sm + h2 * 7168 + dd * 112;
#pragma unroll
        for (int q = 49; q < 56; ++q) *(unsigned short*)(p + q * 2) = 0;
      }
      __syncthreads();
    }
  }

  // ---- attention: wave pair (h, h+8) -> head h; 'half' owns i-tiles {half*2, half*2+1} ----
  const int h    = wave & 7;
  const int half = wave >> 3;
  const float* bias_f = (const float*)(sm + LDS_BIAS);

  // QK^T swapped: D[row=j][col=i]; sc[jt][it], lane: i = itile*16+l15, j = jt*16+ig+r
  float4v sc[4][2];
#pragma unroll
  for (int jt = 0; jt < 4; ++jt)
#pragma unroll
    for (int it = 0; it < 2; ++it) sc[jt][it] = (float4v)0.f;

#pragma unroll
  for (int ks = 0; ks < 2; ++ks) {
    const int dd = ks * 32 + l4 * 8;
    bf16x8 kf[4], qf[2];
#pragma unroll
    for (int jt = 0; jt < 4; ++jt) {
      int s = h * 49 + jt * 16 + l15;            // rows >=49: junk, masked in softmax
      int flat = s * 128 + dd * 2;
      kf[jt] = __builtin_bit_cast(bf16x8, *(const short8*)(sm + LDS_PK + (flat ^ ((s & 7) << 4))));
    }
#pragma unroll
    for (int it = 0; it < 2; ++it) {
      int s = h * 49 + (half * 2 + it) * 16 + l15;
      int flat = s * 128 + dd * 2;
      qf[it] = __builtin_bit_cast(bf16x8, *(const short8*)(sm + LDS_PQ + (flat ^ ((s & 7) << 4))));
    }
#pragma unroll
    for (int jt = 0; jt < 4; ++jt)
#pragma unroll
      for (int it = 0; it < 2; ++it)
        sc[jt][it] = __builtin_amdgcn_mfma_f32_16x16x32_bf16(kf[jt], qf[it], sc[jt][it], 0, 0, 0);
  }

  // softmax: lane holds 16 j-values (jt x r) of column i; reduce in-reg + shfl 16/32
#pragma unroll
  for (int it = 0; it < 2; ++it) {
    int i = (half * 2 + it) * 16 + l15;
    int yi = (i * 37) >> 8, xi = i - yi * 7;
    float mx = -1e30f;
#pragma unroll
    for (int jt = 0; jt < 4; ++jt)
#pragma unroll
      for (int r = 0; r < 4; ++r) {
        int j = jt * 16 + ig + r;
        float v = -1e30f;
        if (i < 49 && j < 49) {
          int yj = (j * 37) >> 8, xj = j - yj * 7;
          int idx = (yi - yj + 6) * 13 + (xi - xj + 6);
          v = sc[jt][it][r] * 0.125f + bias_f[idx * 8 + h];
        }
        sc[jt][it][r] = v;
        mx = fmaxf(mx, v);
      }
    mx = fmaxf(mx, __shfl_xor(mx, 16));
    mx = fmaxf(mx, __shfl_xor(mx, 32));
    float ssum = 0.f;
#pragma unroll
    for (int jt = 0; jt < 4; ++jt)
#pragma unroll
      for (int r = 0; r < 4; ++r) {
        float e = __expf(sc[jt][it][r] - mx);    // -1e30 slots underflow to 0
        sc[jt][it][r] = e;
        ssum += e;
      }
    ssum += __shfl_xor(ssum, 16);
    ssum += __shfl_xor(ssum, 32);
    float inv = 1.f / ssum;
#pragma unroll
    for (int jt = 0; jt < 4; ++jt)
#pragma unroll
      for (int r = 0; r < 4; ++r) sc[jt][it][r] *= inv;
  }

  __syncthreads();  // Pq/Pk dead for ALL waves -> overlay attn (per head, [64][64] bf16 swizzled)
  const int ovb = LDS_PQ + h * 8192;
#pragma unroll
  for (int it = 0; it < 2; ++it) {
    int i = (half * 2 + it) * 16 + l15;
    if (i < 49) {
      int rowb = i * 128;
      int swz = (i & 7) << 4;
#pragma unroll
      for (int jt = 0; jt < 4; ++jt) {
        short4v pk;
#pragma unroll
        for (int r = 0; r < 4; ++r) pk[r] = (short)f2bf(sc[jt][it][r]);
        *(short4v*)(sm + ovb + ((rowb + jt * 32 + ig * 2) ^ swz)) = pk;
      }
    }
  }
  __syncthreads();

  // PV swapped: A = VT (dd-tiles), B = attn (t-tiles); D[row=dd][col=t] = out^T
  float4v oacc[4][2];   // [dt][tt]
#pragma unroll
  for (int dt = 0; dt < 4; ++dt)
#pragma unroll
    for (int tt = 0; tt < 2; ++tt) oacc[dt][tt] = (float4v)0.f;

#pragma unroll
  for (int ks = 0; ks < 2; ++ks) {
    const int tp0 = ks * 32 + l4 * 8;
    const int tc  = (tp0 >= 56) ? 0 : tp0;  // clamp: attn cols >=49 are exact zeros
    bf16x8 vf[4], af[2];
#pragma unroll
    for (int dt = 0; dt < 4; ++dt) {
      int dd = dt * 16 + l15;
      vf[dt] = __builtin_bit_cast(bf16x8, *(const short8*)(sm + h * 7168 + dd * 112 + tc * 2));
    }
#pragma unroll
    for (int tt = 0; tt < 2; ++tt) {
      int t = (half * 2 + tt) * 16 + l15;        // rows >=49: junk cols, discarded
      int flat = t * 128 + tp0 * 2;
      af[tt] = __builtin_bit_cast(bf16x8, *(const short8*)(sm + ovb + (flat ^ ((t & 7) << 4))));
    }
#pragma unroll
    for (int dt = 0; dt < 4; ++dt)
#pragma unroll
      for (int tt = 0; tt < 2; ++tt)
        oacc[dt][tt] = __builtin_amdgcn_mfma_f32_16x16x32_bf16(vf[dt], af[tt], oacc[dt][tt], 0, 0, 0);
  }

  // output: flat [b][wi][h][t'][dd]; float4 stores (r -> 4 consecutive dd)
  float* op = out + (size_t)bwi * 25088 + h * 3136;
#pragma unroll
  for (int tt = 0; tt < 2; ++tt) {
    int t = (half * 2 + tt) * 16 + l15;
    if (t < 49) {
#pragma unroll
      for (int dt = 0; dt < 4; ++dt)
        *(float4v*)(op + t * 64 + dt * 16 + ig) = oacc[dt][tt];
    }
  }
}

extern "C" void kernel_launch(void* const* d_in, const int* in_sizes, int n_in,
                              void* d_out, int out_size, void* d_ws, size_t ws_size,
                              hipStream_t stream) {
  const float* x    = (const float*)d_in[0];
  const float* q_w  = (const float*)d_in[1];
  const float* q_b  = (const float*)d_in[2];
  const float* k_w  = (const float*)d_in[3];
  const float* k_b  = (const float*)d_in[4];
  const float* v_w  = (const float*)d_in[5];
  const float* v_b  = (const float*)d_in[6];
  const float* btab = (const float*)d_in[7];
  short* wcvt = (short*)d_ws;  // 3 * 512 * 512 bf16 = 1.5 MB

  hipLaunchKernelGGL(wconv_kernel, dim3(768), dim3(256), 0, stream, q_w, k_w, v_w, wcvt);
  hipLaunchKernelGGL(wattn_kernel, dim3(1024), dim3(1024), 0, stream,
                     x, wcvt, q_b, k_b, v_b, btab, (float*)d_out);
}